// Round 4
// baseline (215.489 us; speedup 1.0000x reference)
//
#include <hip/hip_runtime.h>
#include <math.h>

// MinGRU: B=8, S=8192, D=256, H=256, fp32 in/out.
//   K0 prep_wfrag : one-shot fp32->bf16 weight conversion into MFMA
//                   fragment layout (16B/lane, L2-resident, 256 KiB).
//   K1 gemm_zh    : bf16-MFMA dual GEMM; x staged via LDS (18 KiB only),
//                   B-fragments loaded DIRECTLY from L2 (no weight LDS,
//                   no per-block weight conversion). Sigmoid epilogue +
//                   fused phase-A emits 16-step subchunk (P,Q) summaries
//                   (free: P[i],Q[i] after the q-butterfly ARE them).
//   K2 phaseB     : sequential scan over 512 subchunk summaries/batch,
//                   batch-32 float2 loads; hstate written IN-PLACE over
//                   pq[].x (no extra ws).
//   K3 phaseC     : replay 16 steps/thread-group, 4 ch/thread via
//                   uint4/float4 (16B/lane loads+stores).
// R1/R2 lesson: register-resident scan across a grid sync always spills.

constexpr int B_ = 8;
constexpr int S_ = 8192;
constexpr int D_ = 256;
constexpr int H_ = 256;
constexpr int M_ = B_ * S_;        // 65536 rows
constexpr int CHUNKS = 128;        // 64-step chunks (gemm wave-half)
constexpr int SUBS = CHUNKS * 4;   // 512 16-step subchunks
constexpr int WF_U4 = 2 * 16 * 4 * 2 * 4 * 16;  // 16384 uint4 = 256 KiB

typedef __attribute__((ext_vector_type(8))) short bf16x8;
typedef __attribute__((ext_vector_type(4))) float f32x4;

// 2 floats -> 2 bf16 (round-to-nearest, ties-away): 2 adds + 1 v_perm.
// lo16 = bf16(f0), hi16 = bf16(f1).
__device__ __forceinline__ uint pack2bf(float f0, float f1) {
  const uint u0 = __float_as_uint(f0) + 0x8000u;
  const uint u1 = __float_as_uint(f1) + 0x8000u;
  return __builtin_amdgcn_perm(u1, u0, 0x07060302u);
}

__device__ __forceinline__ float a_of(uint u) { return __uint_as_float(u << 16); }
__device__ __forceinline__ float b_of(uint u) { return __uint_as_float(u & 0xFFFF0000u); }

// ------------------------------------------------------------- weights ----
// Fragment layout: u = ((((proj*16+ncg)*4+k0b)*2+ks)*4+q)*16+cn  (uint4 idx)
// lane part (q*16+cn) == lane  ->  per-fragment 64-lane read = 1 KiB contig.
__global__ __launch_bounds__(256) void prep_wfrag(
    const float* __restrict__ wzw, const float* __restrict__ whw,
    uint4* __restrict__ wf)
{
  const int u = blockIdx.x * 256 + threadIdx.x;  // 0..16383
  const int cn   = u & 15;
  const int q    = (u >> 4) & 3;
  const int ks   = (u >> 6) & 1;
  const int k0b  = (u >> 7) & 3;
  const int ncg  = (u >> 9) & 15;
  const int proj = u >> 13;
  const float* w = proj ? whw : wzw;
  const float* src = w + (size_t)(ncg * 16 + cn) * D_ + k0b * 64 + ks * 32 + q * 8;
  uint4 r;
  r.x = pack2bf(src[0], src[1]);
  r.y = pack2bf(src[2], src[3]);
  r.z = pack2bf(src[4], src[5]);
  r.w = pack2bf(src[6], src[7]);
  wf[u] = r;
}

// ---------------------------------------------------------------- GEMM ----
// Block: 256 thr = 4 waves. Tile: 128 rows x 64 h-channels, both projections.
// LDS: x only, rows padded to 72 bf16 (conflict-free b128 fragment reads).
// Wave w: rows mb..mb+63 (one 64-step chunk), channels nb..nb+31.
__global__ __launch_bounds__(256) void gemm_zh(
    const float* __restrict__ x,
    const float* __restrict__ whb, const float* __restrict__ wzb,
    const uint4* __restrict__ wf,
    uint* __restrict__ ab, float2* __restrict__ pq)
{
  __shared__ ushort xs[128][72];

  const int tid = threadIdx.x;
  // XCD swizzle: one 128-row x-panel per XCD group -> x L2-local.
  const int g    = blockIdx.x;
  const int xcd  = g & 7;
  const int loc  = g >> 3;
  const int nt   = loc & 3;
  const int panel = (loc >> 2) * 8 + xcd;
  const int m0 = panel * 128;
  const int n0 = nt * 64;

  const int lane = tid & 63;
  const int w  = tid >> 6;
  const int mb = (w & 1) * 64;
  const int nb = (w >> 1) * 32;
  const int q  = lane >> 4;
  const int cn = lane & 15;

  const uint4* wfz = wf;                 // proj 0
  const uint4* wfh = wf + (WF_U4 / 2);   // proj 1
  const int ncg0 = nt * 4 + (w >> 1) * 2;  // +j -> 16-ch group index

  f32x4 accz[4][2] = {};
  f32x4 acch[4][2] = {};

  for (int k0b = 0; k0b < 4; k0b++) {
    __syncthreads();  // WAR guard on LDS reuse
#pragma unroll
    for (int f = 0; f < 8; f++) {  // x: 128 rows x 64 k
      const int idx = tid + 256 * f;
      const int row = idx >> 4, seg = idx & 15;
      float4 v = *(const float4*)(x + (size_t)(m0 + row) * D_ + k0b * 64 + seg * 4);
      *(uint2*)&xs[row][seg * 4] =
          make_uint2(pack2bf(v.x, v.y), pack2bf(v.z, v.w));
    }
    __syncthreads();
#pragma unroll
    for (int ks = 0; ks < 2; ks++) {
      const int kk = ks * 32 + q * 8;  // A[m=lane&15][k=quad*8+j]
      bf16x8 af[4], bz[2], bh[2];
#pragma unroll
      for (int i = 0; i < 4; i++)
        af[i] = *(const bf16x8*)&xs[mb + i * 16 + cn][kk];
#pragma unroll
      for (int j = 0; j < 2; j++) {
        const int o = (((ncg0 + j) * 4 + k0b) * 2 + ks) * 64 + lane;
        bz[j] = *(const bf16x8*)&wfz[o];
        bh[j] = *(const bf16x8*)&wfh[o];
      }
#pragma unroll
      for (int i = 0; i < 4; i++)
#pragma unroll
        for (int j = 0; j < 2; j++) {
          accz[i][j] = __builtin_amdgcn_mfma_f32_16x16x32_bf16(af[i], bz[j], accz[i][j], 0, 0, 0);
          acch[i][j] = __builtin_amdgcn_mfma_f32_16x16x32_bf16(af[i], bh[j], acch[i][j], 0, 0, 0);
        }
    }
  }

  // Chunk identity for this wave (chunks never cross batch: 8192%64==0).
  const int row0 = m0 + mb;
  const int bb2  = row0 >> 13;          // batch
  const int cc   = (row0 & 8191) >> 6;  // chunk within batch

  // Epilogue: C/D col=lane&15, row=quad*4+reg. a=1-z=e*rcp, b=z*h~.
  // t within chunk = i*16 + q*4 + r (ascending in i, q, r).
#pragma unroll
  for (int j = 0; j < 2; j++) {
    const int ch = n0 + nb + j * 16 + cn;
    const float zb = wzb[ch], hb = whb[ch];
    uint u[4][4];
#pragma unroll
    for (int i = 0; i < 4; i++) {
#pragma unroll
      for (int r = 0; r < 4; r++) {
        const int row = m0 + mb + i * 16 + q * 4 + r;
        const float zpre = accz[i][j][r] + zb;
        const float hpre = acch[i][j][r] + hb;
        const float e = __expf(-zpre);
        const float rcp = __builtin_amdgcn_rcpf(1.0f + e);  // z
        const uint pk = pack2bf(e * rcp, hpre * rcp);
        ab[(size_t)row * H_ + ch] = pk;
        u[i][r] = pk;
      }
    }
    // ---- fused phase A: 16-step subchunk (P,Q), bit-identical math to a
    // sequential scan of the packed bf16 values (fp32 composition).
    float P[4], Q[4];
#pragma unroll
    for (int i = 0; i < 4; i++) {
      float Pi = 1.f, Qi = 0.f;
#pragma unroll
      for (int r = 0; r < 4; r++) {
        const float a  = a_of(u[i][r]);
        const float bv = b_of(u[i][r]);
        Qi = fmaf(a, Qi, bv);
        Pi *= a;
      }
      P[i] = Pi; Q[i] = Qi;
    }
    // combine(first,second): P = P1*P2, Q = fma(P2, Q1, Q2). t-order aware.
#pragma unroll
    for (int i = 0; i < 4; i++) {
      {  // partner q^1 (lane^16)
        const float Pp = __shfl_xor(P[i], 16);
        const float Qp = __shfl_xor(Q[i], 16);
        const bool later = (lane & 16) != 0;
        Q[i] = later ? fmaf(P[i], Qp, Q[i]) : fmaf(Pp, Q[i], Qp);
        P[i] = P[i] * Pp;
      }
      {  // partner q^2 (lane^32)
        const float Pp = __shfl_xor(P[i], 32);
        const float Qp = __shfl_xor(Q[i], 32);
        const bool later = (lane & 32) != 0;
        Q[i] = later ? fmaf(P[i], Qp, Q[i]) : fmaf(Pp, Q[i], Qp);
        P[i] = P[i] * Pp;
      }
    }
    // P[i],Q[i] now = full summary of subchunk cc*4+i. One lane per channel.
    if (lane < 16) {
#pragma unroll
      for (int i = 0; i < 4; i++)
        pq[((size_t)bb2 * SUBS + cc * 4 + i) * H_ + ch] = make_float2(P[i], Q[i]);
    }
  }
}

// ---------------------------------------------------------------- scans ---
// Phase B: sequential scan over 512 subchunk summaries, batch-32.
// hstate (h at subchunk start) overwrites pq[].x in place.
__global__ __launch_bounds__(256) void scan_phaseB(
    const float* __restrict__ h0in, float2* __restrict__ pq)
{
  const int b = blockIdx.x;
  const int h = threadIdx.x;
  float2* base = pq + (size_t)b * SUBS * H_ + h;
  float hc = h0in[(size_t)b * H_ + h];
  for (int c0 = 0; c0 < SUBS; c0 += 32) {
    float2 v[32];
#pragma unroll
    for (int j = 0; j < 32; j++)
      v[j] = base[(size_t)(c0 + j) * H_];
#pragma unroll
    for (int j = 0; j < 32; j++) {
      *(float*)&base[(size_t)(c0 + j) * H_] = hc;  // hstate -> .x (in place)
      hc = fmaf(v[j].x, hc, v[j].y);
    }
  }
}

// Phase C: replay. Block = (chunk, b); 4 t-groups x 64 threads;
// 4 channels/thread (uint4 in, float4 out, 16B/lane).
__global__ __launch_bounds__(256) void scan_phaseC(
    const uint* __restrict__ ab, const float2* __restrict__ pq,
    float* __restrict__ out)
{
  const int c = blockIdx.x;
  const int b = blockIdx.y;
  const int gq  = threadIdx.x >> 6;   // t-group (16 steps)
  const int c64 = threadIdx.x & 63;   // channel quad
  const int ch4 = c64 * 4;
  const int sub = c * 4 + gq;
  const size_t ebase = ((size_t)b * S_ + (size_t)sub * 16) * H_ + ch4;

  const float2* hs = pq + ((size_t)b * SUBS + sub) * H_ + ch4;
  float h0v = hs[0].x, h1v = hs[1].x, h2v = hs[2].x, h3v = hs[3].x;

#pragma unroll
  for (int half = 0; half < 2; half++) {
    uint4 v[8];
#pragma unroll
    for (int j = 0; j < 8; j++)
      v[j] = *(const uint4*)(ab + ebase + (size_t)(half * 8 + j) * H_);
#pragma unroll
    for (int j = 0; j < 8; j++) {
      float4 o;
      o.x = h0v = fmaf(a_of(v[j].x), h0v, b_of(v[j].x));
      o.y = h1v = fmaf(a_of(v[j].y), h1v, b_of(v[j].y));
      o.z = h2v = fmaf(a_of(v[j].z), h2v, b_of(v[j].z));
      o.w = h3v = fmaf(a_of(v[j].w), h3v, b_of(v[j].w));
      *(float4*)(out + ebase + (size_t)(half * 8 + j) * H_) = o;
    }
  }
}

extern "C" void kernel_launch(void* const* d_in, const int* in_sizes, int n_in,
                              void* d_out, int out_size, void* d_ws, size_t ws_size,
                              hipStream_t stream) {
  const float* x   = (const float*)d_in[0];
  const float* h0  = (const float*)d_in[1];
  const float* whw = (const float*)d_in[2];
  const float* whb = (const float*)d_in[3];
  const float* wzw = (const float*)d_in[4];
  const float* wzb = (const float*)d_in[5];
  float* out = (float*)d_out;

  uint*   ab = (uint*)d_ws;                           // [M,H] packed bf16 {b,a}
  float2* pq = (float2*)(ab + (size_t)M_ * H_);       // [B,SUBS,H] (P,Q)->(h,Q)
  uint4*  wf = (uint4*)(pq + (size_t)B_ * SUBS * H_); // [16384] weight frags

  prep_wfrag<<<WF_U4 / 256, 256, 0, stream>>>(wzw, whw, wf);
  gemm_zh<<<(M_ / 128) * 4, 256, 0, stream>>>(x, whb, wzb, wf, ab, pq);
  scan_phaseB<<<B_, 256, 0, stream>>>(h0, pq);
  scan_phaseC<<<dim3(CHUNKS, B_), 256, 0, stream>>>(ab, pq, out);
}

// Round 5
// 185.165 us; speedup vs baseline: 1.1638x; 1.1638x over previous
//
#include <hip/hip_runtime.h>
#include <math.h>

// MinGRU: B=8, S=8192, D=256, H=256, fp32 in/out.
//   K1 gemm_zh : bf16-MFMA dual GEMM (z,h) + sigmoid epilogue + FUSED
//                phase-A (chunk (P,Q) via ordered shfl_xor butterfly).
//                == R3 kernel exactly (69.5 us proven).
//   K2 phaseB  : sequential scan over 128 chunk summaries (float2,
//                batch-16) -> hstate.  == R3 kernel exactly.
//   K3 phaseC  : replay; block = 4 chunks x 64 lanes; thread = 4 channels
//                x 64 steps; uint4 loads / float4 stores (16B/lane).
// R4 lessons: direct-L2 weight fragments stall MFMA (keep LDS staging);
// subchunk granularity quadruples phaseB's serial chain (keep chunks=128).
// R1/R2 lesson: register-resident scan across a grid sync always spills.

constexpr int B_ = 8;
constexpr int S_ = 8192;
constexpr int D_ = 256;
constexpr int H_ = 256;
constexpr int M_ = B_ * S_;        // 65536 rows
constexpr int CHUNKS = 128;
constexpr int CLEN = S_ / CHUNKS;  // 64

typedef __attribute__((ext_vector_type(8))) short bf16x8;
typedef __attribute__((ext_vector_type(4))) float f32x4;

// 2 floats -> 2 bf16 (round-to-nearest, ties-away): 2 adds + 1 v_perm.
// lo16 = bf16(f0), hi16 = bf16(f1).
__device__ __forceinline__ uint pack2bf(float f0, float f1) {
  const uint u0 = __float_as_uint(f0) + 0x8000u;
  const uint u1 = __float_as_uint(f1) + 0x8000u;
  return __builtin_amdgcn_perm(u1, u0, 0x07060302u);
}

__device__ __forceinline__ float a_of(uint u) { return __uint_as_float(u << 16); }
__device__ __forceinline__ float b_of(uint u) { return __uint_as_float(u & 0xFFFF0000u); }

// ---------------------------------------------------------------- GEMM ----
// Block: 256 thr = 4 waves. Tile: 128 rows x 64 h-channels, both projections.
// LDS rows padded to 72 bf16: conflict-free b128 fragment reads.
// Wave w: rows mb..mb+63 (one 64-step chunk), channels nb..nb+31.
__global__ __launch_bounds__(256) void gemm_zh(
    const float* __restrict__ x,
    const float* __restrict__ whw, const float* __restrict__ whb,
    const float* __restrict__ wzw, const float* __restrict__ wzb,
    uint* __restrict__ ab, float2* __restrict__ chunkPQ)
{
  __shared__ ushort xs[128][72];
  __shared__ ushort wzs[64][72];
  __shared__ ushort whs[64][72];

  const int tid = threadIdx.x;
  // XCD swizzle: one 128-row x-panel per XCD group -> x L2-local.
  const int g    = blockIdx.x;
  const int xcd  = g & 7;
  const int loc  = g >> 3;
  const int nt   = loc & 3;
  const int panel = (loc >> 2) * 8 + xcd;
  const int m0 = panel * 128;
  const int n0 = nt * 64;

  const int lane = tid & 63;
  const int w  = tid >> 6;
  const int mb = (w & 1) * 64;
  const int nb = (w >> 1) * 32;
  const int q  = lane >> 4;
  const int cn = lane & 15;

  f32x4 accz[4][2] = {};
  f32x4 acch[4][2] = {};

  for (int k0 = 0; k0 < D_; k0 += 64) {
    __syncthreads();  // WAR guard on LDS reuse
#pragma unroll
    for (int f = 0; f < 8; f++) {  // x: 128 rows x 64 k
      const int idx = tid + 256 * f;
      const int row = idx >> 4, seg = idx & 15;
      float4 v = *(const float4*)(x + (size_t)(m0 + row) * D_ + k0 + seg * 4);
      *(uint2*)&xs[row][seg * 4] =
          make_uint2(pack2bf(v.x, v.y), pack2bf(v.z, v.w));
    }
#pragma unroll
    for (int f = 0; f < 4; f++) {  // weights: 64 rows x 64 k each
      const int idx = tid + 256 * f;
      const int row = idx >> 4, seg = idx & 15;
      float4 vz = *(const float4*)(wzw + (size_t)(n0 + row) * D_ + k0 + seg * 4);
      float4 vh = *(const float4*)(whw + (size_t)(n0 + row) * D_ + k0 + seg * 4);
      *(uint2*)&wzs[row][seg * 4] =
          make_uint2(pack2bf(vz.x, vz.y), pack2bf(vz.z, vz.w));
      *(uint2*)&whs[row][seg * 4] =
          make_uint2(pack2bf(vh.x, vh.y), pack2bf(vh.z, vh.w));
    }
    __syncthreads();
#pragma unroll
    for (int ks = 0; ks < 2; ks++) {
      const int kk = ks * 32 + q * 8;  // A[m=lane&15][k=quad*8+j]
      bf16x8 af[4], bz[2], bh[2];
#pragma unroll
      for (int i = 0; i < 4; i++)
        af[i] = *(const bf16x8*)&xs[mb + i * 16 + cn][kk];
#pragma unroll
      for (int j = 0; j < 2; j++) {
        bz[j] = *(const bf16x8*)&wzs[nb + j * 16 + cn][kk];
        bh[j] = *(const bf16x8*)&whs[nb + j * 16 + cn][kk];
      }
#pragma unroll
      for (int i = 0; i < 4; i++)
#pragma unroll
        for (int j = 0; j < 2; j++) {
          accz[i][j] = __builtin_amdgcn_mfma_f32_16x16x32_bf16(af[i], bz[j], accz[i][j], 0, 0, 0);
          acch[i][j] = __builtin_amdgcn_mfma_f32_16x16x32_bf16(af[i], bh[j], acch[i][j], 0, 0, 0);
        }
    }
  }

  // Chunk identity for this wave (chunks never cross batch: 8192%64==0).
  const int row0 = m0 + mb;
  const int bb2  = row0 >> 13;          // batch
  const int cc   = (row0 & 8191) >> 6;  // chunk within batch

  // Epilogue: C/D col=lane&15, row=quad*4+reg. a=1-z=e*rcp, b=z*h~.
  // t within chunk = i*16 + q*4 + r (ascending in i, q, r).
#pragma unroll
  for (int j = 0; j < 2; j++) {
    const int ch = n0 + nb + j * 16 + cn;
    const float zb = wzb[ch], hb = whb[ch];
    uint u[4][4];
#pragma unroll
    for (int i = 0; i < 4; i++) {
#pragma unroll
      for (int r = 0; r < 4; r++) {
        const int row = m0 + mb + i * 16 + q * 4 + r;
        const float zpre = accz[i][j][r] + zb;
        const float hpre = acch[i][j][r] + hb;
        const float e = __expf(-zpre);
        const float rcp = __builtin_amdgcn_rcpf(1.0f + e);  // z
        const uint pk = pack2bf(e * rcp, hpre * rcp);
        ab[(size_t)row * H_ + ch] = pk;
        u[i][r] = pk;
      }
    }
    // ---- fused phase A: (P,Q) over the 64-step chunk, composed from the
    // packed bf16 values in fp32 (bit-identical to a sequential scan).
    float P[4], Q[4];
#pragma unroll
    for (int i = 0; i < 4; i++) {
      float Pi = 1.f, Qi = 0.f;
#pragma unroll
      for (int r = 0; r < 4; r++) {
        const float a  = a_of(u[i][r]);
        const float bv = b_of(u[i][r]);
        Qi = fmaf(a, Qi, bv);
        Pi *= a;
      }
      P[i] = Pi; Q[i] = Qi;
    }
    // combine(first,second): P = P1*P2, Q = fma(P2, Q1, Q2). t-order aware.
#pragma unroll
    for (int i = 0; i < 4; i++) {
      {  // partner q^1 (lane^16)
        const float Pp = __shfl_xor(P[i], 16);
        const float Qp = __shfl_xor(Q[i], 16);
        const bool later = (lane & 16) != 0;
        Q[i] = later ? fmaf(P[i], Qp, Q[i]) : fmaf(Pp, Q[i], Qp);
        P[i] = P[i] * Pp;
      }
      {  // partner q^2 (lane^32)
        const float Pp = __shfl_xor(P[i], 32);
        const float Qp = __shfl_xor(Q[i], 32);
        const bool later = (lane & 32) != 0;
        Q[i] = later ? fmaf(P[i], Qp, Q[i]) : fmaf(Pp, Q[i], Qp);
        P[i] = P[i] * Pp;
      }
    }
    float Pc = P[0], Qc = Q[0];
#pragma unroll
    for (int i = 1; i < 4; i++) {
      Qc = fmaf(P[i], Qc, Q[i]);
      Pc *= P[i];
    }
    if (lane < 16)  // one lane per channel (cn==lane, q==0)
      chunkPQ[((size_t)bb2 * CHUNKS + cc) * H_ + ch] = make_float2(Pc, Qc);
  }
}

// ---------------------------------------------------------------- scans ---
// Phase B: sequential scan over chunk summaries, batch-16 float2 loads.
__global__ __launch_bounds__(256) void scan_phaseB(
    const float* __restrict__ h0in, const float2* __restrict__ pq,
    float* __restrict__ hstate)
{
  const int b = blockIdx.x;
  const int h = threadIdx.x;
  const size_t base = (size_t)b * CHUNKS * H_ + h;
  float hc = h0in[(size_t)b * H_ + h];
  for (int c0 = 0; c0 < CHUNKS; c0 += 16) {
    float2 v[16];
#pragma unroll
    for (int j = 0; j < 16; j++)
      v[j] = pq[base + (size_t)(c0 + j) * H_];
#pragma unroll
    for (int j = 0; j < 16; j++) {
      hstate[base + (size_t)(c0 + j) * H_] = hc;
      hc = fmaf(v[j].x, hc, v[j].y);
    }
  }
}

// Phase C: replay. Block = 4 chunks x 64 lanes; thread = 4 channels x 64
// steps. uint4 loads / float4 stores: 16B/lane, 1KiB/wave per t-row.
__global__ __launch_bounds__(256) void scan_phaseC(
    const uint* __restrict__ ab, const float* __restrict__ hstate,
    float* __restrict__ out)
{
  const int cid = blockIdx.x * 4 + (threadIdx.x >> 6);  // global chunk id
  const int b = cid >> 7;
  const int c = cid & (CHUNKS - 1);
  const int ch4 = (threadIdx.x & 63) * 4;
  const size_t ebase = ((size_t)b * S_ + (size_t)c * CLEN) * H_ + ch4;

  float4 h4 = *(const float4*)(hstate + ((size_t)b * CHUNKS + c) * H_ + ch4);
  float h0v = h4.x, h1v = h4.y, h2v = h4.z, h3v = h4.w;

#pragma unroll
  for (int t0 = 0; t0 < CLEN; t0 += 8) {
    uint4 v[8];
#pragma unroll
    for (int j = 0; j < 8; j++)
      v[j] = *(const uint4*)(ab + ebase + (size_t)(t0 + j) * H_);
#pragma unroll
    for (int j = 0; j < 8; j++) {
      float4 o;
      o.x = h0v = fmaf(a_of(v[j].x), h0v, b_of(v[j].x));
      o.y = h1v = fmaf(a_of(v[j].y), h1v, b_of(v[j].y));
      o.z = h2v = fmaf(a_of(v[j].z), h2v, b_of(v[j].z));
      o.w = h3v = fmaf(a_of(v[j].w), h3v, b_of(v[j].w));
      *(float4*)(out + ebase + (size_t)(t0 + j) * H_) = o;
    }
  }
}

extern "C" void kernel_launch(void* const* d_in, const int* in_sizes, int n_in,
                              void* d_out, int out_size, void* d_ws, size_t ws_size,
                              hipStream_t stream) {
  const float* x   = (const float*)d_in[0];
  const float* h0  = (const float*)d_in[1];
  const float* whw = (const float*)d_in[2];
  const float* whb = (const float*)d_in[3];
  const float* wzw = (const float*)d_in[4];
  const float* wzb = (const float*)d_in[5];
  float* out = (float*)d_out;

  uint*   ab      = (uint*)d_ws;                          // [M,H] packed bf16
  float2* chunkPQ = (float2*)(ab + (size_t)M_ * H_);      // [B,CHUNKS,H]
  float*  hstate  = (float*)(chunkPQ + (size_t)B_ * CHUNKS * H_);  // [B,CHUNKS,H]

  gemm_zh<<<(M_ / 128) * 4, 256, 0, stream>>>(x, whw, whb, wzw, wzb, ab, chunkPQ);
  scan_phaseB<<<B_, 256, 0, stream>>>(h0, (const float2*)chunkPQ, hstate);
  scan_phaseC<<<(B_ * CHUNKS) / 4, 256, 0, stream>>>(ab, hstate, out);
}